// Round 14
// baseline (562.430 us; speedup 1.0000x reference)
//
#include <hip/hip_runtime.h>
#include <stdint.h>

typedef __attribute__((ext_vector_type(8))) short bf16x8;
typedef __attribute__((ext_vector_type(4))) float f32x4;

#define DEV __device__ __forceinline__

static constexpr int Bsz = 4, Lsz = 2048, Esz = 1024, Hsz = 16, HDsz = 64;
static constexpr int BL = Bsz * Lsz;              // 8192 rows
static constexpr size_t PLANE = (size_t)BL * Esz; // 8,388,608 elements
static constexpr size_t WPLANE = (size_t)Esz * Esz; // 1,048,576 elements

DEV unsigned short f2bf(float x) {
  union { float f; unsigned u; } c; c.f = x;
  unsigned u = c.u + 0x7FFFu + ((c.u >> 16) & 1u);
  return (unsigned short)(u >> 16);
}
DEV float bf2f(unsigned short h) {
  union { unsigned u; float f; } c; c.u = ((unsigned)h) << 16; return c.f;
}
DEV bf16x8 ld_bf8(const unsigned short* p) { return *(const bf16x8*)p; }

// ---------------------------------------------------------------------------
// W pre-conversion: f32 -> bf16 hi + lo residual planes (done once; GEMM
// blocks then stage W with plain ushort4 copies). Same f2bf math as the
// in-GEMM conversion => downstream results bit-identical.
// ---------------------------------------------------------------------------
__global__ __launch_bounds__(256) void prep_w(
    const float* __restrict__ W0, const float* __restrict__ W1,
    const float* __restrict__ W2, const float* __restrict__ W3,
    unsigned short* __restrict__ hi, unsigned short* __restrict__ lo)
{
  const float* Ws[4] = {W0, W1, W2, W3};
  size_t i = (size_t)blockIdx.x * 256 + threadIdx.x;   // float4 index
  // 4 matrices x 1M elements / 4 = 1,048,576 float4s total
  for (size_t s = i; s < (size_t)4 * WPLANE / 4; s += (size_t)gridDim.x * 256) {
    int m = (int)(s / (WPLANE / 4));
    size_t off = (s % (WPLANE / 4)) * 4;
    float4 v = *(const float4*)&Ws[m][off];
    ushort4 h, l;
    h.x = f2bf(v.x); l.x = f2bf(v.x - bf2f(h.x));
    h.y = f2bf(v.y); l.y = f2bf(v.y - bf2f(h.y));
    h.z = f2bf(v.z); l.z = f2bf(v.z - bf2f(h.z));
    h.w = f2bf(v.w); l.w = f2bf(v.w - bf2f(h.w));
    *(ushort4*)&hi[m * WPLANE + off] = h;
    *(ushort4*)&lo[m * WPLANE + off] = l;
  }
}

// ---------------------------------------------------------------------------
// NT GEMM with bias: C[M,N] = A[M,K] * W[N,K]^T + bias.
// W from pre-converted bf16 hi/lo planes (2 MFMA). A f32->bf16 inline (proj)
// or already bf16 (out-proj).
// ---------------------------------------------------------------------------
template<bool A_F32, bool OUT_F32>
__global__ __launch_bounds__(256) void gemm_nt(
    const void* __restrict__ Aptr, const unsigned short* __restrict__ Whi,
    const unsigned short* __restrict__ Wlo, const float* __restrict__ bias,
    void* __restrict__ Cptr)
{
  constexpr int Kdim = Esz, Ndim = Esz;
  __shared__ unsigned short As[128][40];
  __shared__ unsigned short Bs[2][128][40];

  const int t = threadIdx.x;
  const int lane = t & 63, wave = t >> 6;
  const int wr = wave >> 1, wc = wave & 1;
  const int frow = lane & 15, fg = lane >> 4;

  const int f = blockIdx.x + 8 * blockIdx.y;          // [0,512)
  const int m_t = ((f & 7) << 3) + (f >> 6);          // 0..63
  const int n_t = (f >> 3) & 7;                       // 0..7
  const int m0 = m_t * 128, n0 = n_t * 128;

  f32x4 acc[4][4];
#pragma unroll
  for (int i = 0; i < 4; i++)
#pragma unroll
    for (int j = 0; j < 4; j++) acc[i][j] = f32x4{0.f, 0.f, 0.f, 0.f};

  for (int k0 = 0; k0 < Kdim; k0 += 32) {
    __syncthreads();
#pragma unroll
    for (int j = 0; j < 4; j++) {
      int s = t + j * 256, row = s >> 3, c4 = s & 7;
      if constexpr (A_F32) {
        const float* A = (const float*)Aptr;
        float4 v = *(const float4*)&A[(size_t)(m0 + row) * Kdim + k0 + c4 * 4];
        ushort4 hi;
        hi.x = f2bf(v.x); hi.y = f2bf(v.y); hi.z = f2bf(v.z); hi.w = f2bf(v.w);
        *(ushort4*)&As[row][c4 * 4] = hi;
      } else {
        const unsigned short* A = (const unsigned short*)Aptr;
        *(ushort4*)&As[row][c4 * 4] =
            *(const ushort4*)&A[(size_t)(m0 + row) * Kdim + k0 + c4 * 4];
      }
      size_t w = (size_t)(n0 + row) * Kdim + k0 + c4 * 4;
      *(ushort4*)&Bs[0][row][c4 * 4] = *(const ushort4*)&Whi[w];
      *(ushort4*)&Bs[1][row][c4 * 4] = *(const ushort4*)&Wlo[w];
    }
    __syncthreads();

    bf16x8 ah[4], bhv[4], blv[4];
#pragma unroll
    for (int x = 0; x < 4; x++) {
      ah[x] = ld_bf8(&As[wr * 64 + x * 16 + frow][fg * 8]);
      bhv[x] = ld_bf8(&Bs[0][wc * 64 + x * 16 + frow][fg * 8]);
      blv[x] = ld_bf8(&Bs[1][wc * 64 + x * 16 + frow][fg * 8]);
    }
#pragma unroll
    for (int mi = 0; mi < 4; mi++)
#pragma unroll
      for (int ni = 0; ni < 4; ni++) {
        acc[mi][ni] = __builtin_amdgcn_mfma_f32_16x16x32_bf16(ah[mi], bhv[ni], acc[mi][ni], 0, 0, 0);
        acc[mi][ni] = __builtin_amdgcn_mfma_f32_16x16x32_bf16(ah[mi], blv[ni], acc[mi][ni], 0, 0, 0);
      }
  }

  // C/D layout: col = lane&15, row = (lane>>4)*4 + reg
#pragma unroll
  for (int mi = 0; mi < 4; mi++)
#pragma unroll
    for (int ni = 0; ni < 4; ni++) {
      int col = n0 + wc * 64 + ni * 16 + frow;
      float bv = bias[col];
#pragma unroll
      for (int r = 0; r < 4; r++) {
        int row = m0 + wr * 64 + mi * 16 + fg * 4 + r;
        float val = acc[mi][ni][r] + bv;
        size_t idx = (size_t)row * Ndim + col;
        if constexpr (OUT_F32) ((float*)Cptr)[idx] = val;
        else                   ((unsigned short*)Cptr)[idx] = f2bf(val);
      }
    }
}

// ---------------------------------------------------------------------------
// Fused attention — R13 numerics verbatim; Kl buffer removed (pass A back to
// R10's proven 2-barrier + T14 register-prefetch, single K buffer).
// LDS = QP + Kh + Vt = 27648 B.
// ---------------------------------------------------------------------------
__global__ __launch_bounds__(256) void attn_fused(
    const unsigned short* __restrict__ qph, const unsigned short* __restrict__ kph,
    const unsigned short* __restrict__ vp,
    float* __restrict__ attn, unsigned short* __restrict__ oh)
{
  __shared__ unsigned short QP[64][72];      // Q-hi at setup; Ps in pass B
  __shared__ unsigned short Kh[64][72];
  __shared__ unsigned short Vt[64][72];      // transposed: [d][k]

  const int t = threadIdx.x, lane = t & 63, wave = t >> 6;
  const int frow = lane & 15, fg = lane >> 4;

  const int f = blockIdx.x + 32 * blockIdx.y;       // [0,2048)
  const int bh = ((f & 7) << 3) + (f >> 8);         // 0..63
  const int qt = (f >> 3) & 31;                     // 0..31
  const int b = bh >> 4, h = bh & 15;
  const int q0 = qt * 64;
  const int qw = q0 + wave * 16;

  const size_t base = (size_t)b * Lsz * Esz + (size_t)h * HDsz;
  constexpr float SC2 = 0.1803368801f;  // 0.125 * log2(e)

  const int srow = t >> 4, sc4 = (t & 15) * 4;
  const int vrow = t >> 4, vc = t & 15;

  auto loadKh = [&](ushort4* r, int row0) {
#pragma unroll
    for (int j = 0; j < 4; j++)
      r[j] = *(const ushort4*)&kph[base + (size_t)(row0 + srow + j * 16) * Esz + sc4];
  };
  auto writeK = [&](const ushort4* r) {
#pragma unroll
    for (int j = 0; j < 4; j++)
      *(ushort4*)&Kh[srow + j * 16][sc4] = r[j];
  };
  auto loadV = [&](unsigned short (*rv)[4], int row0) {
#pragma unroll
    for (int j = 0; j < 4; j++) {
      size_t g = base + (size_t)(row0 + vrow + j * 16) * Esz + vc;
#pragma unroll
      for (int i = 0; i < 4; i++) rv[j][i] = vp[g + i * 16];
    }
  };
  auto writeV = [&](unsigned short (*rv)[4]) {
#pragma unroll
    for (int j = 0; j < 4; j++) {
#pragma unroll
      for (int i = 0; i < 4; i++) Vt[vc + i * 16][vrow + j * 16] = rv[j][i];
    }
  };

  // ---- stage Q (hi -> QP) ----
#pragma unroll
  for (int j = 0; j < 4; j++) {
    size_t g = base + (size_t)(q0 + srow + j * 16) * Esz + sc4;
    *(ushort4*)&QP[srow + j * 16][sc4] = *(const ushort4*)&qph[g];
  }
  __syncthreads();
  bf16x8 qfh[2];
#pragma unroll
  for (int dh = 0; dh < 2; dh++)
    qfh[dh] = ld_bf8(&QP[wave * 16 + frow][dh * 32 + fg * 8]);

  float zl[4];
#pragma unroll
  for (int r = 0; r < 4; r++) zl[r] = 0.f;

  auto computeA = [&]() {
#pragma unroll
    for (int kc = 0; kc < 4; kc++) {
      f32x4 sv = f32x4{0.f, 0.f, 0.f, 0.f};
#pragma unroll
      for (int dh = 0; dh < 2; dh++) {
        bf16x8 kf = ld_bf8(&Kh[kc * 16 + frow][dh * 32 + fg * 8]);
        sv = __builtin_amdgcn_mfma_f32_16x16x32_bf16(qfh[dh], kf, sv, 0, 0, 0);
      }
#pragma unroll
      for (int r = 0; r < 4; r++) zl[r] += exp2f(sv[r] * SC2);
    }
  };

  // ---- pass A: Z only; single K buffer, T14 reg prefetch (R10-proven) ----
  {
    ushort4 rA[4], rB[4];
    loadKh(rA, 0);
    for (int kt = 0; kt < 32; kt += 2) {
      __syncthreads();                 // prev compute done reading Kh (or qf)
      writeK(rA);
      if (kt + 1 < 32) loadKh(rB, (kt + 1) * 64);
      __syncthreads();
      computeA();
      __syncthreads();
      writeK(rB);
      if (kt + 2 < 32) loadKh(rA, (kt + 2) * 64);
      __syncthreads();
      computeA();
    }
  }
  float rz[4];
#pragma unroll
  for (int r = 0; r < 4; r++) {
    float z = zl[r];
#pragma unroll
    for (int o = 1; o < 16; o <<= 1) z += __shfl_xor(z, o);
    rz[r] = 1.f / z;
  }

  f32x4 oacc[4];
#pragma unroll
  for (int d = 0; d < 4; d++) oacc[d] = f32x4{0.f, 0.f, 0.f, 0.f};

  const size_t arow = (size_t)bh * Lsz * Lsz;

  auto computeB = [&](int kt) {
    f32x4 sv[4];
#pragma unroll
    for (int kc = 0; kc < 4; kc++) {
      sv[kc] = f32x4{0.f, 0.f, 0.f, 0.f};
#pragma unroll
      for (int dh = 0; dh < 2; dh++) {
        bf16x8 kfh = ld_bf8(&Kh[kc * 16 + frow][dh * 32 + fg * 8]);
        sv[kc] = __builtin_amdgcn_mfma_f32_16x16x32_bf16(qfh[dh], kfh, sv[kc], 0, 0, 0);
      }
    }
#pragma unroll
    for (int kc = 0; kc < 4; kc++) {
#pragma unroll
      for (int r = 0; r < 4; r++) {
        float p = exp2f(sv[kc][r] * SC2) * rz[r];
        int qrow = qw + fg * 4 + r;
        __builtin_nontemporal_store(p, &attn[arow + (size_t)qrow * Lsz + kt * 64 + kc * 16 + frow]);
        QP[wave * 16 + fg * 4 + r][kc * 16 + frow] = f2bf(p);
      }
    }
    __syncthreads();  // Ps visibility (proven skeleton)
#pragma unroll
    for (int kh2 = 0; kh2 < 2; kh2++) {
      bf16x8 pa = ld_bf8(&QP[wave * 16 + frow][kh2 * 32 + fg * 8]);
#pragma unroll
      for (int d = 0; d < 4; d++) {
        bf16x8 vb = ld_bf8(&Vt[d * 16 + frow][kh2 * 32 + fg * 8]);
        oacc[d] = __builtin_amdgcn_mfma_f32_16x16x32_bf16(pa, vb, oacc[d], 0, 0, 0);
      }
    }
  };

  // ---- pass B: pipelined K+V staging (R12/R13 skeleton, 2x unroll) ----
  {
    ushort4 khA[4], khB[4];
    unsigned short vA[4][4], vB[4][4];
    loadKh(khA, 0);
    loadV(vA, 0);
    for (int kt = 0; kt < 32; kt += 2) {
      __syncthreads();                 // prev PV done reading Vt; scores done Kh
      writeK(khA);
      writeV(vA);
      if (kt + 1 < 32) {
        loadKh(khB, (kt + 1) * 64);
        loadV(vB, (kt + 1) * 64);
      }
      __syncthreads();
      computeB(kt);
      __syncthreads();
      writeK(khB);
      writeV(vB);
      if (kt + 2 < 32) {
        loadKh(khA, (kt + 2) * 64);
        loadV(vA, (kt + 2) * 64);
      }
      __syncthreads();
      computeB(kt + 1);
    }
  }

  // write oh (bf16, [B,L,H,HD] head-interleaved), nontemporal
#pragma unroll
  for (int d = 0; d < 4; d++)
#pragma unroll
    for (int r = 0; r < 4; r++) {
      int qrow = qw + fg * 4 + r;
      __builtin_nontemporal_store(f2bf(oacc[d][r]),
          &oh[base + (size_t)qrow * Esz + d * 16 + frow]);
    }
}

// ---------------------------------------------------------------------------
extern "C" void kernel_launch(void* const* d_in, const int* in_sizes, int n_in,
                              void* d_out, int out_size, void* d_ws, size_t ws_size,
                              hipStream_t stream)
{
  (void)in_sizes; (void)n_in; (void)out_size; (void)ws_size;

  const float* q  = (const float*)d_in[0];
  const float* k  = (const float*)d_in[1];
  const float* v  = (const float*)d_in[2];
  const float* Wq = (const float*)d_in[3];
  const float* bq = (const float*)d_in[4];
  const float* Wk = (const float*)d_in[5];
  const float* bk = (const float*)d_in[6];
  const float* Wv = (const float*)d_in[7];
  const float* bv = (const float*)d_in[8];
  const float* Wo = (const float*)d_in[9];
  const float* bo = (const float*)d_in[10];

  float* out  = (float*)d_out;
  float* attn = out + PLANE;  // output 1 follows output 0, flat

  unsigned short* qph = (unsigned short*)d_ws;
  unsigned short* kph = qph + PLANE;
  unsigned short* vpp = kph + PLANE;
  unsigned short* oh  = vpp + PLANE;
  unsigned short* whi = oh  + PLANE;           // 4 x WPLANE hi
  unsigned short* wlo = whi + 4 * WPLANE;      // 4 x WPLANE lo  (total 80 MB)

  dim3 bb(256);
  prep_w<<<dim3(1024), bb, 0, stream>>>(Wq, Wk, Wv, Wo, whi, wlo);

  dim3 gg(8, 64);
  gemm_nt<true, false><<<gg, bb, 0, stream>>>(q, whi + 0 * WPLANE, wlo + 0 * WPLANE, bq, qph);
  gemm_nt<true, false><<<gg, bb, 0, stream>>>(k, whi + 1 * WPLANE, wlo + 1 * WPLANE, bk, kph);
  gemm_nt<true, false><<<gg, bb, 0, stream>>>(v, whi + 2 * WPLANE, wlo + 2 * WPLANE, bv, vpp);

  dim3 ga(32, 64);
  attn_fused<<<ga, bb, 0, stream>>>(qph, kph, vpp, attn, oh);

  gemm_nt<false, true><<<gg, bb, 0, stream>>>(oh, whi + 3 * WPLANE, wlo + 3 * WPLANE, bo, out);
}

// Round 15
// 519.568 us; speedup vs baseline: 1.0825x; 1.0825x over previous
//
#include <hip/hip_runtime.h>
#include <stdint.h>

typedef __attribute__((ext_vector_type(8))) short bf16x8;
typedef __attribute__((ext_vector_type(4))) float f32x4;

#define DEV __device__ __forceinline__

static constexpr int Bsz = 4, Lsz = 2048, Esz = 1024, Hsz = 16, HDsz = 64;
static constexpr int BL = Bsz * Lsz;              // 8192 rows
static constexpr size_t PLANE = (size_t)BL * Esz; // 8,388,608 elements

DEV unsigned short f2bf(float x) {
  union { float f; unsigned u; } c; c.f = x;
  unsigned u = c.u + 0x7FFFu + ((c.u >> 16) & 1u);
  return (unsigned short)(u >> 16);
}
DEV float bf2f(unsigned short h) {
  union { unsigned u; float f; } c; c.u = ((unsigned)h) << 16; return c.f;
}
DEV bf16x8 ld_bf8(const unsigned short* p) { return *(const bf16x8*)p; }

// ---------------------------------------------------------------------------
// NT GEMM with bias: C[M,N] = A[M,K] * W[N,K]^T + bias.
// W_SPLIT: W in bf16 hi+lo (2 MFMA) — used for the out-projection only.
// Proj GEMMs use W hi-only (1 MFMA): qp/kp/vp's own bf16 storage rounding
// dominates the dropped term (analysis R15; R12 validated the method).
// ---------------------------------------------------------------------------
template<bool A_F32, bool W_SPLIT, bool OUT_F32>
__global__ __launch_bounds__(256) void gemm_nt(
    const void* __restrict__ Aptr, const float* __restrict__ W,
    const float* __restrict__ bias, void* __restrict__ Cptr)
{
  constexpr int Kdim = Esz, Ndim = Esz;
  __shared__ unsigned short As[128][40];
  __shared__ unsigned short Bs[W_SPLIT ? 2 : 1][128][40];

  const int t = threadIdx.x;
  const int lane = t & 63, wave = t >> 6;
  const int wr = wave >> 1, wc = wave & 1;
  const int frow = lane & 15, fg = lane >> 4;

  const int f = blockIdx.x + 8 * blockIdx.y;          // [0,512)
  const int m_t = ((f & 7) << 3) + (f >> 6);          // 0..63
  const int n_t = (f >> 3) & 7;                       // 0..7
  const int m0 = m_t * 128, n0 = n_t * 128;

  f32x4 acc[4][4];
#pragma unroll
  for (int i = 0; i < 4; i++)
#pragma unroll
    for (int j = 0; j < 4; j++) acc[i][j] = f32x4{0.f, 0.f, 0.f, 0.f};

  for (int k0 = 0; k0 < Kdim; k0 += 32) {
    __syncthreads();
#pragma unroll
    for (int j = 0; j < 4; j++) {
      int s = t + j * 256, row = s >> 3, c4 = s & 7;
      if constexpr (A_F32) {
        const float* A = (const float*)Aptr;
        float4 v = *(const float4*)&A[(size_t)(m0 + row) * Kdim + k0 + c4 * 4];
        ushort4 hi;
        hi.x = f2bf(v.x); hi.y = f2bf(v.y); hi.z = f2bf(v.z); hi.w = f2bf(v.w);
        *(ushort4*)&As[row][c4 * 4] = hi;
      } else {
        const unsigned short* A = (const unsigned short*)Aptr;
        *(ushort4*)&As[row][c4 * 4] =
            *(const ushort4*)&A[(size_t)(m0 + row) * Kdim + k0 + c4 * 4];
      }
      {
        float4 v = *(const float4*)&W[(size_t)(n0 + row) * Kdim + k0 + c4 * 4];
        ushort4 hi;
        hi.x = f2bf(v.x); hi.y = f2bf(v.y); hi.z = f2bf(v.z); hi.w = f2bf(v.w);
        *(ushort4*)&Bs[0][row][c4 * 4] = hi;
        if constexpr (W_SPLIT) {
          ushort4 lo;
          lo.x = f2bf(v.x - bf2f(hi.x));
          lo.y = f2bf(v.y - bf2f(hi.y));
          lo.z = f2bf(v.z - bf2f(hi.z));
          lo.w = f2bf(v.w - bf2f(hi.w));
          *(ushort4*)&Bs[W_SPLIT ? 1 : 0][row][c4 * 4] = lo;
        }
      }
    }
    __syncthreads();

    bf16x8 ah[4], bhv[4], blv[4];
#pragma unroll
    for (int x = 0; x < 4; x++) {
      ah[x] = ld_bf8(&As[wr * 64 + x * 16 + frow][fg * 8]);
      bhv[x] = ld_bf8(&Bs[0][wc * 64 + x * 16 + frow][fg * 8]);
      if constexpr (W_SPLIT)
        blv[x] = ld_bf8(&Bs[W_SPLIT ? 1 : 0][wc * 64 + x * 16 + frow][fg * 8]);
    }
#pragma unroll
    for (int mi = 0; mi < 4; mi++)
#pragma unroll
      for (int ni = 0; ni < 4; ni++) {
        acc[mi][ni] = __builtin_amdgcn_mfma_f32_16x16x32_bf16(ah[mi], bhv[ni], acc[mi][ni], 0, 0, 0);
        if constexpr (W_SPLIT)
          acc[mi][ni] = __builtin_amdgcn_mfma_f32_16x16x32_bf16(ah[mi], blv[ni], acc[mi][ni], 0, 0, 0);
      }
  }

  // C/D layout: col = lane&15, row = (lane>>4)*4 + reg
#pragma unroll
  for (int mi = 0; mi < 4; mi++)
#pragma unroll
    for (int ni = 0; ni < 4; ni++) {
      int col = n0 + wc * 64 + ni * 16 + frow;
      float bv = bias[col];
#pragma unroll
      for (int r = 0; r < 4; r++) {
        int row = m0 + wr * 64 + mi * 16 + fg * 4 + r;
        float val = acc[mi][ni][r] + bv;
        size_t idx = (size_t)row * Ndim + col;
        if constexpr (OUT_F32) ((float*)Cptr)[idx] = val;
        else                   ((unsigned short*)Cptr)[idx] = f2bf(val);
      }
    }
}

// ---------------------------------------------------------------------------
// Fused attention — R14 verbatim (27.6 KB LDS; hi-only scores, m=0;
// T14 register-prefetch staging; nt-stores for attn/oh).
// ---------------------------------------------------------------------------
__global__ __launch_bounds__(256) void attn_fused(
    const unsigned short* __restrict__ qph, const unsigned short* __restrict__ kph,
    const unsigned short* __restrict__ vp,
    float* __restrict__ attn, unsigned short* __restrict__ oh)
{
  __shared__ unsigned short QP[64][72];      // Q-hi at setup; Ps in pass B
  __shared__ unsigned short Kh[64][72];
  __shared__ unsigned short Vt[64][72];      // transposed: [d][k]

  const int t = threadIdx.x, lane = t & 63, wave = t >> 6;
  const int frow = lane & 15, fg = lane >> 4;

  const int f = blockIdx.x + 32 * blockIdx.y;       // [0,2048)
  const int bh = ((f & 7) << 3) + (f >> 8);         // 0..63
  const int qt = (f >> 3) & 31;                     // 0..31
  const int b = bh >> 4, h = bh & 15;
  const int q0 = qt * 64;
  const int qw = q0 + wave * 16;

  const size_t base = (size_t)b * Lsz * Esz + (size_t)h * HDsz;
  constexpr float SC2 = 0.1803368801f;  // 0.125 * log2(e)

  const int srow = t >> 4, sc4 = (t & 15) * 4;
  const int vrow = t >> 4, vc = t & 15;

  auto loadKh = [&](ushort4* r, int row0) {
#pragma unroll
    for (int j = 0; j < 4; j++)
      r[j] = *(const ushort4*)&kph[base + (size_t)(row0 + srow + j * 16) * Esz + sc4];
  };
  auto writeK = [&](const ushort4* r) {
#pragma unroll
    for (int j = 0; j < 4; j++)
      *(ushort4*)&Kh[srow + j * 16][sc4] = r[j];
  };
  auto loadV = [&](unsigned short (*rv)[4], int row0) {
#pragma unroll
    for (int j = 0; j < 4; j++) {
      size_t g = base + (size_t)(row0 + vrow + j * 16) * Esz + vc;
#pragma unroll
      for (int i = 0; i < 4; i++) rv[j][i] = vp[g + i * 16];
    }
  };
  auto writeV = [&](unsigned short (*rv)[4]) {
#pragma unroll
    for (int j = 0; j < 4; j++) {
#pragma unroll
      for (int i = 0; i < 4; i++) Vt[vc + i * 16][vrow + j * 16] = rv[j][i];
    }
  };

  // ---- stage Q (hi -> QP) ----
#pragma unroll
  for (int j = 0; j < 4; j++) {
    size_t g = base + (size_t)(q0 + srow + j * 16) * Esz + sc4;
    *(ushort4*)&QP[srow + j * 16][sc4] = *(const ushort4*)&qph[g];
  }
  __syncthreads();
  bf16x8 qfh[2];
#pragma unroll
  for (int dh = 0; dh < 2; dh++)
    qfh[dh] = ld_bf8(&QP[wave * 16 + frow][dh * 32 + fg * 8]);

  float zl[4];
#pragma unroll
  for (int r = 0; r < 4; r++) zl[r] = 0.f;

  auto computeA = [&]() {
#pragma unroll
    for (int kc = 0; kc < 4; kc++) {
      f32x4 sv = f32x4{0.f, 0.f, 0.f, 0.f};
#pragma unroll
      for (int dh = 0; dh < 2; dh++) {
        bf16x8 kf = ld_bf8(&Kh[kc * 16 + frow][dh * 32 + fg * 8]);
        sv = __builtin_amdgcn_mfma_f32_16x16x32_bf16(qfh[dh], kf, sv, 0, 0, 0);
      }
#pragma unroll
      for (int r = 0; r < 4; r++) zl[r] += exp2f(sv[r] * SC2);
    }
  };

  // ---- pass A: Z only; single K buffer, T14 reg prefetch ----
  {
    ushort4 rA[4], rB[4];
    loadKh(rA, 0);
    for (int kt = 0; kt < 32; kt += 2) {
      __syncthreads();                 // prev compute done reading Kh (or qf)
      writeK(rA);
      if (kt + 1 < 32) loadKh(rB, (kt + 1) * 64);
      __syncthreads();
      computeA();
      __syncthreads();
      writeK(rB);
      if (kt + 2 < 32) loadKh(rA, (kt + 2) * 64);
      __syncthreads();
      computeA();
    }
  }
  float rz[4];
#pragma unroll
  for (int r = 0; r < 4; r++) {
    float z = zl[r];
#pragma unroll
    for (int o = 1; o < 16; o <<= 1) z += __shfl_xor(z, o);
    rz[r] = 1.f / z;
  }

  f32x4 oacc[4];
#pragma unroll
  for (int d = 0; d < 4; d++) oacc[d] = f32x4{0.f, 0.f, 0.f, 0.f};

  const size_t arow = (size_t)bh * Lsz * Lsz;

  auto computeB = [&](int kt) {
    f32x4 sv[4];
#pragma unroll
    for (int kc = 0; kc < 4; kc++) {
      sv[kc] = f32x4{0.f, 0.f, 0.f, 0.f};
#pragma unroll
      for (int dh = 0; dh < 2; dh++) {
        bf16x8 kfh = ld_bf8(&Kh[kc * 16 + frow][dh * 32 + fg * 8]);
        sv[kc] = __builtin_amdgcn_mfma_f32_16x16x32_bf16(qfh[dh], kfh, sv[kc], 0, 0, 0);
      }
    }
#pragma unroll
    for (int kc = 0; kc < 4; kc++) {
#pragma unroll
      for (int r = 0; r < 4; r++) {
        float p = exp2f(sv[kc][r] * SC2) * rz[r];
        int qrow = qw + fg * 4 + r;
        __builtin_nontemporal_store(p, &attn[arow + (size_t)qrow * Lsz + kt * 64 + kc * 16 + frow]);
        QP[wave * 16 + fg * 4 + r][kc * 16 + frow] = f2bf(p);
      }
    }
    __syncthreads();  // Ps visibility (proven skeleton)
#pragma unroll
    for (int kh2 = 0; kh2 < 2; kh2++) {
      bf16x8 pa = ld_bf8(&QP[wave * 16 + frow][kh2 * 32 + fg * 8]);
#pragma unroll
      for (int d = 0; d < 4; d++) {
        bf16x8 vb = ld_bf8(&Vt[d * 16 + frow][kh2 * 32 + fg * 8]);
        oacc[d] = __builtin_amdgcn_mfma_f32_16x16x32_bf16(pa, vb, oacc[d], 0, 0, 0);
      }
    }
  };

  // ---- pass B: pipelined K+V staging (2x unroll) ----
  {
    ushort4 khA[4], khB[4];
    unsigned short vA[4][4], vB[4][4];
    loadKh(khA, 0);
    loadV(vA, 0);
    for (int kt = 0; kt < 32; kt += 2) {
      __syncthreads();                 // prev PV done reading Vt; scores done Kh
      writeK(khA);
      writeV(vA);
      if (kt + 1 < 32) {
        loadKh(khB, (kt + 1) * 64);
        loadV(vB, (kt + 1) * 64);
      }
      __syncthreads();
      computeB(kt);
      __syncthreads();
      writeK(khB);
      writeV(vB);
      if (kt + 2 < 32) {
        loadKh(khA, (kt + 2) * 64);
        loadV(vA, (kt + 2) * 64);
      }
      __syncthreads();
      computeB(kt + 1);
    }
  }

  // write oh (bf16, [B,L,H,HD] head-interleaved), nontemporal
#pragma unroll
  for (int d = 0; d < 4; d++)
#pragma unroll
    for (int r = 0; r < 4; r++) {
      int qrow = qw + fg * 4 + r;
      __builtin_nontemporal_store(f2bf(oacc[d][r]),
          &oh[base + (size_t)qrow * Esz + d * 16 + frow]);
    }
}

// ---------------------------------------------------------------------------
extern "C" void kernel_launch(void* const* d_in, const int* in_sizes, int n_in,
                              void* d_out, int out_size, void* d_ws, size_t ws_size,
                              hipStream_t stream)
{
  (void)in_sizes; (void)n_in; (void)out_size; (void)ws_size;

  const float* q  = (const float*)d_in[0];
  const float* k  = (const float*)d_in[1];
  const float* v  = (const float*)d_in[2];
  const float* Wq = (const float*)d_in[3];
  const float* bq = (const float*)d_in[4];
  const float* Wk = (const float*)d_in[5];
  const float* bk = (const float*)d_in[6];
  const float* Wv = (const float*)d_in[7];
  const float* bv = (const float*)d_in[8];
  const float* Wo = (const float*)d_in[9];
  const float* bo = (const float*)d_in[10];

  float* out  = (float*)d_out;
  float* attn = out + PLANE;  // output 1 follows output 0, flat

  unsigned short* qph = (unsigned short*)d_ws;
  unsigned short* kph = qph + PLANE;
  unsigned short* vpp = kph + PLANE;
  unsigned short* oh  = vpp + PLANE;

  dim3 gg(8, 64), bb(256);
  // proj GEMMs: W hi-only (1 MFMA) — qp/kp/vp bf16 storage rounding dominates
  gemm_nt<true, false, false><<<gg, bb, 0, stream>>>(q, Wq, bq, qph);
  gemm_nt<true, false, false><<<gg, bb, 0, stream>>>(k, Wk, bk, kph);
  gemm_nt<true, false, false><<<gg, bb, 0, stream>>>(v, Wv, bv, vpp);

  dim3 ga(32, 64);
  attn_fused<<<ga, bb, 0, stream>>>(qph, kph, vpp, attn, oh);

  // out-projection: W split (2 MFMA) — writes output 0 directly
  gemm_nt<false, true, true><<<gg, bb, 0, stream>>>(oh, Wo, bo, out);
}

// Round 17
// 475.079 us; speedup vs baseline: 1.1839x; 1.0936x over previous
//
#include <hip/hip_runtime.h>
#include <stdint.h>

typedef __attribute__((ext_vector_type(8))) short bf16x8;
typedef __attribute__((ext_vector_type(4))) float f32x4;

#define DEV __device__ __forceinline__

static constexpr int Bsz = 4, Lsz = 2048, Esz = 1024, Hsz = 16, HDsz = 64;
static constexpr int BL = Bsz * Lsz;              // 8192 rows
static constexpr size_t PLANE = (size_t)BL * Esz; // 8,388,608 elements

DEV unsigned short f2bf(float x) {
  union { float f; unsigned u; } c; c.f = x;
  unsigned u = c.u + 0x7FFFu + ((c.u >> 16) & 1u);
  return (unsigned short)(u >> 16);
}
DEV float bf2f(unsigned short h) {
  union { unsigned u; float f; } c; c.u = ((unsigned)h) << 16; return c.f;
}
DEV bf16x8 ld_bf8(const unsigned short* p) { return *(const bf16x8*)p; }

// ---------------------------------------------------------------------------
// NT GEMM with bias (VERBATIM from R15): C = A * W^T + bias.
// Proj: W hi-only (1 MFMA). Out-proj: W split hi/lo (2 MFMA).
// ---------------------------------------------------------------------------
template<bool A_F32, bool W_SPLIT, bool OUT_F32>
__global__ __launch_bounds__(256) void gemm_nt(
    const void* __restrict__ Aptr, const float* __restrict__ W,
    const float* __restrict__ bias, void* __restrict__ Cptr)
{
  constexpr int Kdim = Esz, Ndim = Esz;
  __shared__ unsigned short As[128][40];
  __shared__ unsigned short Bs[W_SPLIT ? 2 : 1][128][40];

  const int t = threadIdx.x;
  const int lane = t & 63, wave = t >> 6;
  const int wr = wave >> 1, wc = wave & 1;
  const int frow = lane & 15, fg = lane >> 4;

  const int f = blockIdx.x + 8 * blockIdx.y;          // [0,512)
  const int m_t = ((f & 7) << 3) + (f >> 6);          // 0..63
  const int n_t = (f >> 3) & 7;                       // 0..7
  const int m0 = m_t * 128, n0 = n_t * 128;

  f32x4 acc[4][4];
#pragma unroll
  for (int i = 0; i < 4; i++)
#pragma unroll
    for (int j = 0; j < 4; j++) acc[i][j] = f32x4{0.f, 0.f, 0.f, 0.f};

  for (int k0 = 0; k0 < Kdim; k0 += 32) {
    __syncthreads();
#pragma unroll
    for (int j = 0; j < 4; j++) {
      int s = t + j * 256, row = s >> 3, c4 = s & 7;
      if constexpr (A_F32) {
        const float* A = (const float*)Aptr;
        float4 v = *(const float4*)&A[(size_t)(m0 + row) * Kdim + k0 + c4 * 4];
        ushort4 hi;
        hi.x = f2bf(v.x); hi.y = f2bf(v.y); hi.z = f2bf(v.z); hi.w = f2bf(v.w);
        *(ushort4*)&As[row][c4 * 4] = hi;
      } else {
        const unsigned short* A = (const unsigned short*)Aptr;
        *(ushort4*)&As[row][c4 * 4] =
            *(const ushort4*)&A[(size_t)(m0 + row) * Kdim + k0 + c4 * 4];
      }
      {
        float4 v = *(const float4*)&W[(size_t)(n0 + row) * Kdim + k0 + c4 * 4];
        ushort4 hi;
        hi.x = f2bf(v.x); hi.y = f2bf(v.y); hi.z = f2bf(v.z); hi.w = f2bf(v.w);
        *(ushort4*)&Bs[0][row][c4 * 4] = hi;
        if constexpr (W_SPLIT) {
          ushort4 lo;
          lo.x = f2bf(v.x - bf2f(hi.x));
          lo.y = f2bf(v.y - bf2f(hi.y));
          lo.z = f2bf(v.z - bf2f(hi.z));
          lo.w = f2bf(v.w - bf2f(hi.w));
          *(ushort4*)&Bs[W_SPLIT ? 1 : 0][row][c4 * 4] = lo;
        }
      }
    }
    __syncthreads();

    bf16x8 ah[4], bhv[4], blv[4];
#pragma unroll
    for (int x = 0; x < 4; x++) {
      ah[x] = ld_bf8(&As[wr * 64 + x * 16 + frow][fg * 8]);
      bhv[x] = ld_bf8(&Bs[0][wc * 64 + x * 16 + frow][fg * 8]);
      if constexpr (W_SPLIT)
        blv[x] = ld_bf8(&Bs[W_SPLIT ? 1 : 0][wc * 64 + x * 16 + frow][fg * 8]);
    }
#pragma unroll
    for (int mi = 0; mi < 4; mi++)
#pragma unroll
      for (int ni = 0; ni < 4; ni++) {
        acc[mi][ni] = __builtin_amdgcn_mfma_f32_16x16x32_bf16(ah[mi], bhv[ni], acc[mi][ni], 0, 0, 0);
        if constexpr (W_SPLIT)
          acc[mi][ni] = __builtin_amdgcn_mfma_f32_16x16x32_bf16(ah[mi], blv[ni], acc[mi][ni], 0, 0, 0);
      }
  }

  // C/D layout: col = lane&15, row = (lane>>4)*4 + reg
#pragma unroll
  for (int mi = 0; mi < 4; mi++)
#pragma unroll
    for (int ni = 0; ni < 4; ni++) {
      int col = n0 + wc * 64 + ni * 16 + frow;
      float bv = bias[col];
#pragma unroll
      for (int r = 0; r < 4; r++) {
        int row = m0 + wr * 64 + mi * 16 + fg * 4 + r;
        float val = acc[mi][ni][r] + bv;
        size_t idx = (size_t)row * Ndim + col;
        if constexpr (OUT_F32) ((float*)Cptr)[idx] = val;
        else                   ((unsigned short*)Cptr)[idx] = f2bf(val);
      }
    }
}

// ---------------------------------------------------------------------------
// Fused attention — R15 skeleton + two changes:
//  * pass A: 128 K-rows per phase through Kh AND Vt (Vt idle in pass A):
//    1 barrier/tile, 16 MFMA + 32 exp per phase, 8 loads in flight.
//  * pass B: attn written AFTER the Ps barrier from the bf16 Ps values with
//    fully-coalesced f32x4 nt-stores (256B/16 lanes); PV overlaps the drain.
//    attn = f32(bf16(p)) — consistent with PV's P, +<=6e-4 abs.
// ---------------------------------------------------------------------------
__global__ __launch_bounds__(256) void attn_fused(
    const unsigned short* __restrict__ qph, const unsigned short* __restrict__ kph,
    const unsigned short* __restrict__ vp,
    float* __restrict__ attn, unsigned short* __restrict__ oh)
{
  __shared__ unsigned short QP[64][72];      // Q-hi at setup; Ps in pass B
  __shared__ unsigned short Kh[64][72];
  __shared__ unsigned short Vt[64][72];      // pass-A K dbuf; pass-B V^T

  const int t = threadIdx.x, lane = t & 63, wave = t >> 6;
  const int frow = lane & 15, fg = lane >> 4;

  const int f = blockIdx.x + 32 * blockIdx.y;       // [0,2048)
  const int bh = ((f & 7) << 3) + (f >> 8);         // 0..63
  const int qt = (f >> 3) & 31;                     // 0..31
  const int b = bh >> 4, h = bh & 15;
  const int q0 = qt * 64;
  const int qw = q0 + wave * 16;

  const size_t base = (size_t)b * Lsz * Esz + (size_t)h * HDsz;
  constexpr float SC2 = 0.1803368801f;  // 0.125 * log2(e)

  const int srow = t >> 4, sc4 = (t & 15) * 4;
  const int vrow = t >> 4, vc = t & 15;

  auto loadKh = [&](ushort4* r, int row0) {
#pragma unroll
    for (int j = 0; j < 4; j++)
      r[j] = *(const ushort4*)&kph[base + (size_t)(row0 + srow + j * 16) * Esz + sc4];
  };
  auto writeK = [&](unsigned short (*dst)[72], const ushort4* r) {
#pragma unroll
    for (int j = 0; j < 4; j++)
      *(ushort4*)&dst[srow + j * 16][sc4] = r[j];
  };
  auto loadV = [&](unsigned short (*rv)[4], int row0) {
#pragma unroll
    for (int j = 0; j < 4; j++) {
      size_t g = base + (size_t)(row0 + vrow + j * 16) * Esz + vc;
#pragma unroll
      for (int i = 0; i < 4; i++) rv[j][i] = vp[g + i * 16];
    }
  };
  auto writeV = [&](unsigned short (*rv)[4]) {
#pragma unroll
    for (int j = 0; j < 4; j++) {
#pragma unroll
      for (int i = 0; i < 4; i++) Vt[vc + i * 16][vrow + j * 16] = rv[j][i];
    }
  };

  // ---- stage Q (hi -> QP) ----
#pragma unroll
  for (int j = 0; j < 4; j++) {
    size_t g = base + (size_t)(q0 + srow + j * 16) * Esz + sc4;
    *(ushort4*)&QP[srow + j * 16][sc4] = *(const ushort4*)&qph[g];
  }
  __syncthreads();
  bf16x8 qfh[2];
#pragma unroll
  for (int dh = 0; dh < 2; dh++)
    qfh[dh] = ld_bf8(&QP[wave * 16 + frow][dh * 32 + fg * 8]);

  float zl[4];
#pragma unroll
  for (int r = 0; r < 4; r++) zl[r] = 0.f;

  auto computeA = [&](unsigned short (*Kc)[72]) {
#pragma unroll
    for (int kc = 0; kc < 4; kc++) {
      f32x4 sv = f32x4{0.f, 0.f, 0.f, 0.f};
#pragma unroll
      for (int dh = 0; dh < 2; dh++) {
        bf16x8 kf = ld_bf8(&Kc[kc * 16 + frow][dh * 32 + fg * 8]);
        sv = __builtin_amdgcn_mfma_f32_16x16x32_bf16(qfh[dh], kf, sv, 0, 0, 0);
      }
#pragma unroll
      for (int r = 0; r < 4; r++) zl[r] += exp2f(sv[r] * SC2);
    }
  };

  // ---- pass A: Z only; 128 rows/phase via Kh+Vt, 1 barrier/tile ----
  {
    ushort4 rA[4], rB[4];
    loadKh(rA, 0);
    loadKh(rB, 64);
    for (int kt = 0; kt < 32; kt += 2) {
      __syncthreads();                 // prev compute done reading Kh/Vt (or qf)
      writeK(Kh, rA);
      writeK(Vt, rB);
      if (kt + 2 < 32) {
        loadKh(rA, (kt + 2) * 64);
        loadKh(rB, (kt + 3) * 64);
      }
      __syncthreads();                 // both tiles visible
      computeA(Kh);
      computeA(Vt);
    }
  }
  float rz[4];
#pragma unroll
  for (int r = 0; r < 4; r++) {
    float z = zl[r];
#pragma unroll
    for (int o = 1; o < 16; o <<= 1) z += __shfl_xor(z, o);
    rz[r] = 1.f / z;
  }

  f32x4 oacc[4];
#pragma unroll
  for (int d = 0; d < 4; d++) oacc[d] = f32x4{0.f, 0.f, 0.f, 0.f};

  const size_t arow = (size_t)bh * Lsz * Lsz;

  auto computeB = [&](int kt) {
    f32x4 sv[4];
#pragma unroll
    for (int kc = 0; kc < 4; kc++) {
      sv[kc] = f32x4{0.f, 0.f, 0.f, 0.f};
#pragma unroll
      for (int dh = 0; dh < 2; dh++) {
        bf16x8 kfh = ld_bf8(&Kh[kc * 16 + frow][dh * 32 + fg * 8]);
        sv[kc] = __builtin_amdgcn_mfma_f32_16x16x32_bf16(qfh[dh], kfh, sv[kc], 0, 0, 0);
      }
    }
#pragma unroll
    for (int kc = 0; kc < 4; kc++) {
#pragma unroll
      for (int r = 0; r < 4; r++) {
        float p = exp2f(sv[kc][r] * SC2) * rz[r];
        QP[wave * 16 + fg * 4 + r][kc * 16 + frow] = f2bf(p);
      }
    }
    __syncthreads();  // Ps visibility (proven skeleton)
    // coalesced attn write from Ps: 16 lanes cover one row's 64 cols (256B)
#pragma unroll
    for (int it = 0; it < 4; it++) {
      int prow = it * 4 + fg;           // 0..15 within wave's 16 rows
      int pc = frow * 4;                // col 0..60
      ushort4 pv4 = *(const ushort4*)&QP[wave * 16 + prow][pc];
      f32x4 w;
      w[0] = bf2f(pv4.x); w[1] = bf2f(pv4.y); w[2] = bf2f(pv4.z); w[3] = bf2f(pv4.w);
      __builtin_nontemporal_store(w,
          (f32x4*)&attn[arow + (size_t)(qw + prow) * Lsz + kt * 64 + pc]);
    }
    // PV (overlaps the nt-store drain)
#pragma unroll
    for (int kh2 = 0; kh2 < 2; kh2++) {
      bf16x8 pa = ld_bf8(&QP[wave * 16 + frow][kh2 * 32 + fg * 8]);
#pragma unroll
      for (int d = 0; d < 4; d++) {
        bf16x8 vb = ld_bf8(&Vt[d * 16 + frow][kh2 * 32 + fg * 8]);
        oacc[d] = __builtin_amdgcn_mfma_f32_16x16x32_bf16(pa, vb, oacc[d], 0, 0, 0);
      }
    }
  };

  // ---- pass B: pipelined K+V staging (R15 skeleton, 2x unroll) ----
  {
    ushort4 khA[4], khB[4];
    unsigned short vA[4][4], vB[4][4];
    loadKh(khA, 0);
    loadV(vA, 0);
    for (int kt = 0; kt < 32; kt += 2) {
      __syncthreads();                 // prev PV done reading Vt; scores done Kh
      writeK(Kh, khA);
      writeV(vA);
      if (kt + 1 < 32) {
        loadKh(khB, (kt + 1) * 64);
        loadV(vB, (kt + 1) * 64);
      }
      __syncthreads();
      computeB(kt);
      __syncthreads();
      writeK(Kh, khB);
      writeV(vB);
      if (kt + 2 < 32) {
        loadKh(khA, (kt + 2) * 64);
        loadV(vA, (kt + 2) * 64);
      }
      __syncthreads();
      computeB(kt + 1);
    }
  }

  // write oh (bf16, [B,L,H,HD] head-interleaved), nontemporal
#pragma unroll
  for (int d = 0; d < 4; d++)
#pragma unroll
    for (int r = 0; r < 4; r++) {
      int qrow = qw + fg * 4 + r;
      __builtin_nontemporal_store(f2bf(oacc[d][r]),
          &oh[base + (size_t)qrow * Esz + d * 16 + frow]);
    }
}

// ---------------------------------------------------------------------------
extern "C" void kernel_launch(void* const* d_in, const int* in_sizes, int n_in,
                              void* d_out, int out_size, void* d_ws, size_t ws_size,
                              hipStream_t stream)
{
  (void)in_sizes; (void)n_in; (void)out_size; (void)ws_size;

  const float* q  = (const float*)d_in[0];
  const float* k  = (const float*)d_in[1];
  const float* v  = (const float*)d_in[2];
  const float* Wq = (const float*)d_in[3];
  const float* bq = (const float*)d_in[4];
  const float* Wk = (const float*)d_in[5];
  const float* bk = (const float*)d_in[6];
  const float* Wv = (const float*)d_in[7];
  const float* bv = (const float*)d_in[8];
  const float* Wo = (const float*)d_in[9];
  const float* bo = (const float*)d_in[10];

  float* out  = (float*)d_out;
  float* attn = out + PLANE;  // output 1 follows output 0, flat

  unsigned short* qph = (unsigned short*)d_ws;
  unsigned short* kph = qph + PLANE;
  unsigned short* vpp = kph + PLANE;
  unsigned short* oh  = vpp + PLANE;

  dim3 gg(8, 64), bb(256);
  gemm_nt<true, false, false><<<gg, bb, 0, stream>>>(q, Wq, bq, qph);
  gemm_nt<true, false, false><<<gg, bb, 0, stream>>>(k, Wk, bk, kph);
  gemm_nt<true, false, false><<<gg, bb, 0, stream>>>(v, Wv, bv, vpp);

  dim3 ga(32, 64);
  attn_fused<<<ga, bb, 0, stream>>>(qph, kph, vpp, attn, oh);

  gemm_nt<false, true, true><<<gg, bb, 0, stream>>>(oh, Wo, bo, out);
}

// Round 18
// 463.519 us; speedup vs baseline: 1.2134x; 1.0249x over previous
//
#include <hip/hip_runtime.h>
#include <stdint.h>

typedef __attribute__((ext_vector_type(8))) short bf16x8;
typedef __attribute__((ext_vector_type(4))) float f32x4;

#define DEV __device__ __forceinline__

static constexpr int Bsz = 4, Lsz = 2048, Esz = 1024, Hsz = 16, HDsz = 64;
static constexpr int BL = Bsz * Lsz;              // 8192 rows
static constexpr size_t PLANE = (size_t)BL * Esz; // 8,388,608 elements

DEV unsigned short f2bf(float x) {
  union { float f; unsigned u; } c; c.f = x;
  unsigned u = c.u + 0x7FFFu + ((c.u >> 16) & 1u);
  return (unsigned short)(u >> 16);
}
DEV float bf2f(unsigned short h) {
  union { unsigned u; float f; } c; c.u = ((unsigned)h) << 16; return c.f;
}
DEV bf16x8 ld_bf8(const unsigned short* p) { return *(const bf16x8*)p; }

// ---------------------------------------------------------------------------
// GEMM core (proven R15/R17 structure): C = A * W^T + bias, W hi-only bf16.
// Shared by the fused 3-projection kernel and the out-projection kernel.
// ---------------------------------------------------------------------------
template<bool A_F32, bool OUT_F32>
DEV void gemm_body(const void* __restrict__ Aptr, const float* __restrict__ W,
                   const float* __restrict__ bias, void* __restrict__ Cptr,
                   unsigned short (*As)[40], unsigned short (*Bs)[40])
{
  constexpr int Kdim = Esz, Ndim = Esz;
  const int t = threadIdx.x;
  const int lane = t & 63, wave = t >> 6;
  const int wr = wave >> 1, wc = wave & 1;
  const int frow = lane & 15, fg = lane >> 4;

  const int f = blockIdx.x + 8 * blockIdx.y;          // [0,512)
  const int m_t = ((f & 7) << 3) + (f >> 6);          // 0..63
  const int n_t = (f >> 3) & 7;                       // 0..7
  const int m0 = m_t * 128, n0 = n_t * 128;

  f32x4 acc[4][4];
#pragma unroll
  for (int i = 0; i < 4; i++)
#pragma unroll
    for (int j = 0; j < 4; j++) acc[i][j] = f32x4{0.f, 0.f, 0.f, 0.f};

  for (int k0 = 0; k0 < Kdim; k0 += 32) {
    __syncthreads();
#pragma unroll
    for (int j = 0; j < 4; j++) {
      int s = t + j * 256, row = s >> 3, c4 = s & 7;
      if constexpr (A_F32) {
        const float* A = (const float*)Aptr;
        float4 v = *(const float4*)&A[(size_t)(m0 + row) * Kdim + k0 + c4 * 4];
        ushort4 hi;
        hi.x = f2bf(v.x); hi.y = f2bf(v.y); hi.z = f2bf(v.z); hi.w = f2bf(v.w);
        *(ushort4*)&As[row][c4 * 4] = hi;
      } else {
        const unsigned short* A = (const unsigned short*)Aptr;
        *(ushort4*)&As[row][c4 * 4] =
            *(const ushort4*)&A[(size_t)(m0 + row) * Kdim + k0 + c4 * 4];
      }
      {
        float4 v = *(const float4*)&W[(size_t)(n0 + row) * Kdim + k0 + c4 * 4];
        ushort4 hi;
        hi.x = f2bf(v.x); hi.y = f2bf(v.y); hi.z = f2bf(v.z); hi.w = f2bf(v.w);
        *(ushort4*)&Bs[row][c4 * 4] = hi;
      }
    }
    __syncthreads();

    bf16x8 ah[4], bhv[4];
#pragma unroll
    for (int x = 0; x < 4; x++) {
      ah[x] = ld_bf8(&As[wr * 64 + x * 16 + frow][fg * 8]);
      bhv[x] = ld_bf8(&Bs[wc * 64 + x * 16 + frow][fg * 8]);
    }
#pragma unroll
    for (int mi = 0; mi < 4; mi++)
#pragma unroll
      for (int ni = 0; ni < 4; ni++)
        acc[mi][ni] = __builtin_amdgcn_mfma_f32_16x16x32_bf16(ah[mi], bhv[ni], acc[mi][ni], 0, 0, 0);
  }

  // C/D layout: col = lane&15, row = (lane>>4)*4 + reg
#pragma unroll
  for (int mi = 0; mi < 4; mi++)
#pragma unroll
    for (int ni = 0; ni < 4; ni++) {
      int col = n0 + wc * 64 + ni * 16 + frow;
      float bv = bias[col];
#pragma unroll
      for (int r = 0; r < 4; r++) {
        int row = m0 + wr * 64 + mi * 16 + fg * 4 + r;
        float val = acc[mi][ni][r] + bv;
        size_t idx = (size_t)row * Ndim + col;
        if constexpr (OUT_F32)
          __builtin_nontemporal_store(val, &((float*)Cptr)[idx]);
        else
          ((unsigned short*)Cptr)[idx] = f2bf(val);
      }
    }
}

// Fused q/k/v projections: one launch, grid.z selects the problem.
__global__ __launch_bounds__(256) void gemm_proj3(
    const float* qA, const float* kA, const float* vA,
    const float* Wq, const float* Wk, const float* Wv,
    const float* bq, const float* bk, const float* bv,
    unsigned short* qC, unsigned short* kC, unsigned short* vC)
{
  __shared__ unsigned short As[128][40];
  __shared__ unsigned short Bs[128][40];
  const int z = blockIdx.z;
  const float* A = z == 0 ? qA : (z == 1 ? kA : vA);
  const float* W = z == 0 ? Wq : (z == 1 ? Wk : Wv);
  const float* bias = z == 0 ? bq : (z == 1 ? bk : bv);
  unsigned short* C = z == 0 ? qC : (z == 1 ? kC : vC);
  gemm_body<true, false>(A, W, bias, C, As, Bs);
}

// Out-projection: A bf16, W hi-only, f32 nt-store output.
__global__ __launch_bounds__(256) void gemm_out(
    const unsigned short* A, const float* W, const float* bias, float* C)
{
  __shared__ unsigned short As[128][40];
  __shared__ unsigned short Bs[128][40];
  gemm_body<false, true>(A, W, bias, C, As, Bs);
}

// ---------------------------------------------------------------------------
// Fused attention — R17 VERBATIM (passed, 475 µs).
// ---------------------------------------------------------------------------
__global__ __launch_bounds__(256) void attn_fused(
    const unsigned short* __restrict__ qph, const unsigned short* __restrict__ kph,
    const unsigned short* __restrict__ vp,
    float* __restrict__ attn, unsigned short* __restrict__ oh)
{
  __shared__ unsigned short QP[64][72];      // Q-hi at setup; Ps in pass B
  __shared__ unsigned short Kh[64][72];
  __shared__ unsigned short Vt[64][72];      // pass-A K dbuf; pass-B V^T

  const int t = threadIdx.x, lane = t & 63, wave = t >> 6;
  const int frow = lane & 15, fg = lane >> 4;

  const int f = blockIdx.x + 32 * blockIdx.y;       // [0,2048)
  const int bh = ((f & 7) << 3) + (f >> 8);         // 0..63
  const int qt = (f >> 3) & 31;                     // 0..31
  const int b = bh >> 4, h = bh & 15;
  const int q0 = qt * 64;
  const int qw = q0 + wave * 16;

  const size_t base = (size_t)b * Lsz * Esz + (size_t)h * HDsz;
  constexpr float SC2 = 0.1803368801f;  // 0.125 * log2(e)

  const int srow = t >> 4, sc4 = (t & 15) * 4;
  const int vrow = t >> 4, vc = t & 15;

  auto loadKh = [&](ushort4* r, int row0) {
#pragma unroll
    for (int j = 0; j < 4; j++)
      r[j] = *(const ushort4*)&kph[base + (size_t)(row0 + srow + j * 16) * Esz + sc4];
  };
  auto writeK = [&](unsigned short (*dst)[72], const ushort4* r) {
#pragma unroll
    for (int j = 0; j < 4; j++)
      *(ushort4*)&dst[srow + j * 16][sc4] = r[j];
  };
  auto loadV = [&](unsigned short (*rv)[4], int row0) {
#pragma unroll
    for (int j = 0; j < 4; j++) {
      size_t g = base + (size_t)(row0 + vrow + j * 16) * Esz + vc;
#pragma unroll
      for (int i = 0; i < 4; i++) rv[j][i] = vp[g + i * 16];
    }
  };
  auto writeV = [&](unsigned short (*rv)[4]) {
#pragma unroll
    for (int j = 0; j < 4; j++) {
#pragma unroll
      for (int i = 0; i < 4; i++) Vt[vc + i * 16][vrow + j * 16] = rv[j][i];
    }
  };

  // ---- stage Q (hi -> QP) ----
#pragma unroll
  for (int j = 0; j < 4; j++) {
    size_t g = base + (size_t)(q0 + srow + j * 16) * Esz + sc4;
    *(ushort4*)&QP[srow + j * 16][sc4] = *(const ushort4*)&qph[g];
  }
  __syncthreads();
  bf16x8 qfh[2];
#pragma unroll
  for (int dh = 0; dh < 2; dh++)
    qfh[dh] = ld_bf8(&QP[wave * 16 + frow][dh * 32 + fg * 8]);

  float zl[4];
#pragma unroll
  for (int r = 0; r < 4; r++) zl[r] = 0.f;

  auto computeA = [&](unsigned short (*Kc)[72]) {
#pragma unroll
    for (int kc = 0; kc < 4; kc++) {
      f32x4 sv = f32x4{0.f, 0.f, 0.f, 0.f};
#pragma unroll
      for (int dh = 0; dh < 2; dh++) {
        bf16x8 kf = ld_bf8(&Kc[kc * 16 + frow][dh * 32 + fg * 8]);
        sv = __builtin_amdgcn_mfma_f32_16x16x32_bf16(qfh[dh], kf, sv, 0, 0, 0);
      }
#pragma unroll
      for (int r = 0; r < 4; r++) zl[r] += exp2f(sv[r] * SC2);
    }
  };

  // ---- pass A: Z only; 128 rows/phase via Kh+Vt, 1 barrier/tile ----
  {
    ushort4 rA[4], rB[4];
    loadKh(rA, 0);
    loadKh(rB, 64);
    for (int kt = 0; kt < 32; kt += 2) {
      __syncthreads();                 // prev compute done reading Kh/Vt (or qf)
      writeK(Kh, rA);
      writeK(Vt, rB);
      if (kt + 2 < 32) {
        loadKh(rA, (kt + 2) * 64);
        loadKh(rB, (kt + 3) * 64);
      }
      __syncthreads();                 // both tiles visible
      computeA(Kh);
      computeA(Vt);
    }
  }
  float rz[4];
#pragma unroll
  for (int r = 0; r < 4; r++) {
    float z = zl[r];
#pragma unroll
    for (int o = 1; o < 16; o <<= 1) z += __shfl_xor(z, o);
    rz[r] = 1.f / z;
  }

  f32x4 oacc[4];
#pragma unroll
  for (int d = 0; d < 4; d++) oacc[d] = f32x4{0.f, 0.f, 0.f, 0.f};

  const size_t arow = (size_t)bh * Lsz * Lsz;

  auto computeB = [&](int kt) {
    f32x4 sv[4];
#pragma unroll
    for (int kc = 0; kc < 4; kc++) {
      sv[kc] = f32x4{0.f, 0.f, 0.f, 0.f};
#pragma unroll
      for (int dh = 0; dh < 2; dh++) {
        bf16x8 kfh = ld_bf8(&Kh[kc * 16 + frow][dh * 32 + fg * 8]);
        sv[kc] = __builtin_amdgcn_mfma_f32_16x16x32_bf16(qfh[dh], kfh, sv[kc], 0, 0, 0);
      }
    }
#pragma unroll
    for (int kc = 0; kc < 4; kc++) {
#pragma unroll
      for (int r = 0; r < 4; r++) {
        float p = exp2f(sv[kc][r] * SC2) * rz[r];
        QP[wave * 16 + fg * 4 + r][kc * 16 + frow] = f2bf(p);
      }
    }
    __syncthreads();  // Ps visibility (proven skeleton)
    // coalesced attn write from Ps: 16 lanes cover one row's 64 cols (256B)
#pragma unroll
    for (int it = 0; it < 4; it++) {
      int prow = it * 4 + fg;           // 0..15 within wave's 16 rows
      int pc = frow * 4;                // col 0..60
      ushort4 pv4 = *(const ushort4*)&QP[wave * 16 + prow][pc];
      f32x4 w;
      w[0] = bf2f(pv4.x); w[1] = bf2f(pv4.y); w[2] = bf2f(pv4.z); w[3] = bf2f(pv4.w);
      __builtin_nontemporal_store(w,
          (f32x4*)&attn[arow + (size_t)(qw + prow) * Lsz + kt * 64 + pc]);
    }
    // PV (overlaps the nt-store drain)
#pragma unroll
    for (int kh2 = 0; kh2 < 2; kh2++) {
      bf16x8 pa = ld_bf8(&QP[wave * 16 + frow][kh2 * 32 + fg * 8]);
#pragma unroll
      for (int d = 0; d < 4; d++) {
        bf16x8 vb = ld_bf8(&Vt[d * 16 + frow][kh2 * 32 + fg * 8]);
        oacc[d] = __builtin_amdgcn_mfma_f32_16x16x32_bf16(pa, vb, oacc[d], 0, 0, 0);
      }
    }
  };

  // ---- pass B: pipelined K+V staging (2x unroll) ----
  {
    ushort4 khA[4], khB[4];
    unsigned short vA[4][4], vB[4][4];
    loadKh(khA, 0);
    loadV(vA, 0);
    for (int kt = 0; kt < 32; kt += 2) {
      __syncthreads();                 // prev PV done reading Vt; scores done Kh
      writeK(Kh, khA);
      writeV(vA);
      if (kt + 1 < 32) {
        loadKh(khB, (kt + 1) * 64);
        loadV(vB, (kt + 1) * 64);
      }
      __syncthreads();
      computeB(kt);
      __syncthreads();
      writeK(Kh, khB);
      writeV(vB);
      if (kt + 2 < 32) {
        loadKh(khA, (kt + 2) * 64);
        loadV(vA, (kt + 2) * 64);
      }
      __syncthreads();
      computeB(kt + 1);
    }
  }

  // write oh (bf16, [B,L,H,HD] head-interleaved), nontemporal
#pragma unroll
  for (int d = 0; d < 4; d++)
#pragma unroll
    for (int r = 0; r < 4; r++) {
      int qrow = qw + fg * 4 + r;
      __builtin_nontemporal_store(f2bf(oacc[d][r]),
          &oh[base + (size_t)qrow * Esz + d * 16 + frow]);
    }
}

// ---------------------------------------------------------------------------
extern "C" void kernel_launch(void* const* d_in, const int* in_sizes, int n_in,
                              void* d_out, int out_size, void* d_ws, size_t ws_size,
                              hipStream_t stream)
{
  (void)in_sizes; (void)n_in; (void)out_size; (void)ws_size;

  const float* q  = (const float*)d_in[0];
  const float* k  = (const float*)d_in[1];
  const float* v  = (const float*)d_in[2];
  const float* Wq = (const float*)d_in[3];
  const float* bq = (const float*)d_in[4];
  const float* Wk = (const float*)d_in[5];
  const float* bk = (const float*)d_in[6];
  const float* Wv = (const float*)d_in[7];
  const float* bv = (const float*)d_in[8];
  const float* Wo = (const float*)d_in[9];
  const float* bo = (const float*)d_in[10];

  float* out  = (float*)d_out;
  float* attn = out + PLANE;  // output 1 follows output 0, flat

  unsigned short* qph = (unsigned short*)d_ws;
  unsigned short* kph = qph + PLANE;
  unsigned short* vpp = kph + PLANE;
  unsigned short* oh  = vpp + PLANE;

  dim3 bb(256);
  gemm_proj3<<<dim3(8, 64, 3), bb, 0, stream>>>(q, k, v, Wq, Wk, Wv,
                                                bq, bk, bv, qph, kph, vpp);

  dim3 ga(32, 64);
  attn_fused<<<ga, bb, 0, stream>>>(qph, kph, vpp, attn, oh);

  gemm_out<<<dim3(8, 64), bb, 0, stream>>>(oh, Wo, bo, out);
}

// Round 19
// 458.493 us; speedup vs baseline: 1.2267x; 1.0110x over previous
//
#include <hip/hip_runtime.h>
#include <stdint.h>

typedef __attribute__((ext_vector_type(8))) short bf16x8;
typedef __attribute__((ext_vector_type(4))) float f32x4;

#define DEV __device__ __forceinline__

static constexpr int Bsz = 4, Lsz = 2048, Esz = 1024, Hsz = 16, HDsz = 64;
static constexpr int BL = Bsz * Lsz;              // 8192 rows
static constexpr size_t PLANE = (size_t)BL * Esz; // 8,388,608 elements

DEV unsigned short f2bf(float x) {
  union { float f; unsigned u; } c; c.f = x;
  unsigned u = c.u + 0x7FFFu + ((c.u >> 16) & 1u);
  return (unsigned short)(u >> 16);
}
DEV float bf2f(unsigned short h) {
  union { unsigned u; float f; } c; c.u = ((unsigned)h) << 16; return c.f;
}
DEV bf16x8 ld_bf8(const unsigned short* p) { return *(const bf16x8*)p; }

// ---------------------------------------------------------------------------
// GEMM core (R18-proven): C = A * W^T + bias, W hi-only bf16.
// ---------------------------------------------------------------------------
template<bool A_F32, bool OUT_F32>
DEV void gemm_body(const void* __restrict__ Aptr, const float* __restrict__ W,
                   const float* __restrict__ bias, void* __restrict__ Cptr,
                   unsigned short (*As)[40], unsigned short (*Bs)[40])
{
  constexpr int Kdim = Esz, Ndim = Esz;
  const int t = threadIdx.x;
  const int lane = t & 63, wave = t >> 6;
  const int wr = wave >> 1, wc = wave & 1;
  const int frow = lane & 15, fg = lane >> 4;

  const int f = blockIdx.x + 8 * blockIdx.y;          // [0,512)
  const int m_t = ((f & 7) << 3) + (f >> 6);          // 0..63
  const int n_t = (f >> 3) & 7;                       // 0..7
  const int m0 = m_t * 128, n0 = n_t * 128;

  f32x4 acc[4][4];
#pragma unroll
  for (int i = 0; i < 4; i++)
#pragma unroll
    for (int j = 0; j < 4; j++) acc[i][j] = f32x4{0.f, 0.f, 0.f, 0.f};

  for (int k0 = 0; k0 < Kdim; k0 += 32) {
    __syncthreads();
#pragma unroll
    for (int j = 0; j < 4; j++) {
      int s = t + j * 256, row = s >> 3, c4 = s & 7;
      if constexpr (A_F32) {
        const float* A = (const float*)Aptr;
        float4 v = *(const float4*)&A[(size_t)(m0 + row) * Kdim + k0 + c4 * 4];
        ushort4 hi;
        hi.x = f2bf(v.x); hi.y = f2bf(v.y); hi.z = f2bf(v.z); hi.w = f2bf(v.w);
        *(ushort4*)&As[row][c4 * 4] = hi;
      } else {
        const unsigned short* A = (const unsigned short*)Aptr;
        *(ushort4*)&As[row][c4 * 4] =
            *(const ushort4*)&A[(size_t)(m0 + row) * Kdim + k0 + c4 * 4];
      }
      {
        float4 v = *(const float4*)&W[(size_t)(n0 + row) * Kdim + k0 + c4 * 4];
        ushort4 hi;
        hi.x = f2bf(v.x); hi.y = f2bf(v.y); hi.z = f2bf(v.z); hi.w = f2bf(v.w);
        *(ushort4*)&Bs[row][c4 * 4] = hi;
      }
    }
    __syncthreads();

    bf16x8 ah[4], bhv[4];
#pragma unroll
    for (int x = 0; x < 4; x++) {
      ah[x] = ld_bf8(&As[wr * 64 + x * 16 + frow][fg * 8]);
      bhv[x] = ld_bf8(&Bs[wc * 64 + x * 16 + frow][fg * 8]);
    }
#pragma unroll
    for (int mi = 0; mi < 4; mi++)
#pragma unroll
      for (int ni = 0; ni < 4; ni++)
        acc[mi][ni] = __builtin_amdgcn_mfma_f32_16x16x32_bf16(ah[mi], bhv[ni], acc[mi][ni], 0, 0, 0);
  }

  // C/D layout: col = lane&15, row = (lane>>4)*4 + reg
#pragma unroll
  for (int mi = 0; mi < 4; mi++)
#pragma unroll
    for (int ni = 0; ni < 4; ni++) {
      int col = n0 + wc * 64 + ni * 16 + frow;
      float bv = bias[col];
#pragma unroll
      for (int r = 0; r < 4; r++) {
        int row = m0 + wr * 64 + mi * 16 + fg * 4 + r;
        float val = acc[mi][ni][r] + bv;
        size_t idx = (size_t)row * Ndim + col;
        if constexpr (OUT_F32)
          __builtin_nontemporal_store(val, &((float*)Cptr)[idx]);
        else
          ((unsigned short*)Cptr)[idx] = f2bf(val);
      }
    }
}

// Fused q/k/v projections: one launch, grid.z selects the problem.
__global__ __launch_bounds__(256) void gemm_proj3(
    const float* qA, const float* kA, const float* vA,
    const float* Wq, const float* Wk, const float* Wv,
    const float* bq, const float* bk, const float* bv,
    unsigned short* qC, unsigned short* kC, unsigned short* vC)
{
  __shared__ unsigned short As[128][40];
  __shared__ unsigned short Bs[128][40];
  const int z = blockIdx.z;
  const float* A = z == 0 ? qA : (z == 1 ? kA : vA);
  const float* W = z == 0 ? Wq : (z == 1 ? Wk : Wv);
  const float* bias = z == 0 ? bq : (z == 1 ? bk : bv);
  unsigned short* C = z == 0 ? qC : (z == 1 ? kC : vC);
  gemm_body<true, false>(A, W, bias, C, As, Bs);
}

// Out-projection: A bf16, W hi-only, f32 nt-store output.
__global__ __launch_bounds__(256) void gemm_out(
    const unsigned short* A, const float* W, const float* bias, float* C)
{
  __shared__ unsigned short As[128][40];
  __shared__ unsigned short Bs[128][40];
  gemm_body<false, true>(A, W, bias, C, As, Bs);
}

// ---------------------------------------------------------------------------
// Fused attention — R18 structure; ONE change: the barrier between the
// P-store and the attn-write/PV is removed. All QP accesses in computeB are
// WAVE-LOCAL (P-store, attn-write, and pa reads all touch only the wave's
// own 16-row slice), so same-wave lgkmcnt ordering suffices; the two loop
// barriers still protect the cross-wave Kh/Vt staging hazards.
// ---------------------------------------------------------------------------
__global__ __launch_bounds__(256) void attn_fused(
    const unsigned short* __restrict__ qph, const unsigned short* __restrict__ kph,
    const unsigned short* __restrict__ vp,
    float* __restrict__ attn, unsigned short* __restrict__ oh)
{
  __shared__ unsigned short QP[64][72];      // Q-hi at setup; Ps in pass B
  __shared__ unsigned short Kh[64][72];
  __shared__ unsigned short Vt[64][72];      // pass-A K dbuf; pass-B V^T

  const int t = threadIdx.x, lane = t & 63, wave = t >> 6;
  const int frow = lane & 15, fg = lane >> 4;

  const int f = blockIdx.x + 32 * blockIdx.y;       // [0,2048)
  const int bh = ((f & 7) << 3) + (f >> 8);         // 0..63
  const int qt = (f >> 3) & 31;                     // 0..31
  const int b = bh >> 4, h = bh & 15;
  const int q0 = qt * 64;
  const int qw = q0 + wave * 16;

  const size_t base = (size_t)b * Lsz * Esz + (size_t)h * HDsz;
  constexpr float SC2 = 0.1803368801f;  // 0.125 * log2(e)

  const int srow = t >> 4, sc4 = (t & 15) * 4;
  const int vrow = t >> 4, vc = t & 15;

  auto loadKh = [&](ushort4* r, int row0) {
#pragma unroll
    for (int j = 0; j < 4; j++)
      r[j] = *(const ushort4*)&kph[base + (size_t)(row0 + srow + j * 16) * Esz + sc4];
  };
  auto writeK = [&](unsigned short (*dst)[72], const ushort4* r) {
#pragma unroll
    for (int j = 0; j < 4; j++)
      *(ushort4*)&dst[srow + j * 16][sc4] = r[j];
  };
  auto loadV = [&](unsigned short (*rv)[4], int row0) {
#pragma unroll
    for (int j = 0; j < 4; j++) {
      size_t g = base + (size_t)(row0 + vrow + j * 16) * Esz + vc;
#pragma unroll
      for (int i = 0; i < 4; i++) rv[j][i] = vp[g + i * 16];
    }
  };
  auto writeV = [&](unsigned short (*rv)[4]) {
#pragma unroll
    for (int j = 0; j < 4; j++) {
#pragma unroll
      for (int i = 0; i < 4; i++) Vt[vc + i * 16][vrow + j * 16] = rv[j][i];
    }
  };

  // ---- stage Q (hi -> QP) ----
#pragma unroll
  for (int j = 0; j < 4; j++) {
    size_t g = base + (size_t)(q0 + srow + j * 16) * Esz + sc4;
    *(ushort4*)&QP[srow + j * 16][sc4] = *(const ushort4*)&qph[g];
  }
  __syncthreads();
  bf16x8 qfh[2];
#pragma unroll
  for (int dh = 0; dh < 2; dh++)
    qfh[dh] = ld_bf8(&QP[wave * 16 + frow][dh * 32 + fg * 8]);

  float zl[4];
#pragma unroll
  for (int r = 0; r < 4; r++) zl[r] = 0.f;

  auto computeA = [&](unsigned short (*Kc)[72]) {
#pragma unroll
    for (int kc = 0; kc < 4; kc++) {
      f32x4 sv = f32x4{0.f, 0.f, 0.f, 0.f};
#pragma unroll
      for (int dh = 0; dh < 2; dh++) {
        bf16x8 kf = ld_bf8(&Kc[kc * 16 + frow][dh * 32 + fg * 8]);
        sv = __builtin_amdgcn_mfma_f32_16x16x32_bf16(qfh[dh], kf, sv, 0, 0, 0);
      }
#pragma unroll
      for (int r = 0; r < 4; r++) zl[r] += exp2f(sv[r] * SC2);
    }
  };

  // ---- pass A: Z only; 128 rows/phase via Kh+Vt, 1 barrier/tile ----
  {
    ushort4 rA[4], rB[4];
    loadKh(rA, 0);
    loadKh(rB, 64);
    for (int kt = 0; kt < 32; kt += 2) {
      __syncthreads();                 // prev compute done reading Kh/Vt (or qf)
      writeK(Kh, rA);
      writeK(Vt, rB);
      if (kt + 2 < 32) {
        loadKh(rA, (kt + 2) * 64);
        loadKh(rB, (kt + 3) * 64);
      }
      __syncthreads();                 // both tiles visible
      computeA(Kh);
      computeA(Vt);
    }
  }
  float rz[4];
#pragma unroll
  for (int r = 0; r < 4; r++) {
    float z = zl[r];
#pragma unroll
    for (int o = 1; o < 16; o <<= 1) z += __shfl_xor(z, o);
    rz[r] = 1.f / z;
  }

  f32x4 oacc[4];
#pragma unroll
  for (int d = 0; d < 4; d++) oacc[d] = f32x4{0.f, 0.f, 0.f, 0.f};

  const size_t arow = (size_t)bh * Lsz * Lsz;

  auto computeB = [&](int kt) {
    f32x4 sv[4];
#pragma unroll
    for (int kc = 0; kc < 4; kc++) {
      sv[kc] = f32x4{0.f, 0.f, 0.f, 0.f};
#pragma unroll
      for (int dh = 0; dh < 2; dh++) {
        bf16x8 kfh = ld_bf8(&Kh[kc * 16 + frow][dh * 32 + fg * 8]);
        sv[kc] = __builtin_amdgcn_mfma_f32_16x16x32_bf16(qfh[dh], kfh, sv[kc], 0, 0, 0);
      }
    }
#pragma unroll
    for (int kc = 0; kc < 4; kc++) {
#pragma unroll
      for (int r = 0; r < 4; r++) {
        float p = exp2f(sv[kc][r] * SC2) * rz[r];
        QP[wave * 16 + fg * 4 + r][kc * 16 + frow] = f2bf(p);
      }
    }
    // NO barrier: all QP traffic below is wave-local (lgkmcnt-ordered).
    // coalesced attn write from Ps: 16 lanes cover one row's 64 cols (256B)
#pragma unroll
    for (int it = 0; it < 4; it++) {
      int prow = it * 4 + fg;           // 0..15 within wave's 16 rows
      int pc = frow * 4;                // col 0..60
      ushort4 pv4 = *(const ushort4*)&QP[wave * 16 + prow][pc];
      f32x4 w;
      w[0] = bf2f(pv4.x); w[1] = bf2f(pv4.y); w[2] = bf2f(pv4.z); w[3] = bf2f(pv4.w);
      __builtin_nontemporal_store(w,
          (f32x4*)&attn[arow + (size_t)(qw + prow) * Lsz + kt * 64 + pc]);
    }
    // PV (overlaps the nt-store drain)
#pragma unroll
    for (int kh2 = 0; kh2 < 2; kh2++) {
      bf16x8 pa = ld_bf8(&QP[wave * 16 + frow][kh2 * 32 + fg * 8]);
#pragma unroll
      for (int d = 0; d < 4; d++) {
        bf16x8 vb = ld_bf8(&Vt[d * 16 + frow][kh2 * 32 + fg * 8]);
        oacc[d] = __builtin_amdgcn_mfma_f32_16x16x32_bf16(pa, vb, oacc[d], 0, 0, 0);
      }
    }
  };

  // ---- pass B: pipelined K+V staging (2x unroll, 2 barriers/tile) ----
  {
    ushort4 khA[4], khB[4];
    unsigned short vA[4][4], vB[4][4];
    loadKh(khA, 0);
    loadV(vA, 0);
    for (int kt = 0; kt < 32; kt += 2) {
      __syncthreads();                 // prev PV done reading Vt; scores done Kh
      writeK(Kh, khA);
      writeV(vA);
      if (kt + 1 < 32) {
        loadKh(khB, (kt + 1) * 64);
        loadV(vB, (kt + 1) * 64);
      }
      __syncthreads();
      computeB(kt);
      __syncthreads();
      writeK(Kh, khB);
      writeV(vB);
      if (kt + 2 < 32) {
        loadKh(khA, (kt + 2) * 64);
        loadV(vA, (kt + 2) * 64);
      }
      __syncthreads();
      computeB(kt + 1);
    }
  }

  // write oh (bf16, [B,L,H,HD] head-interleaved), nontemporal
#pragma unroll
  for (int d = 0; d < 4; d++)
#pragma unroll
    for (int r = 0; r < 4; r++) {
      int qrow = qw + fg * 4 + r;
      __builtin_nontemporal_store(f2bf(oacc[d][r]),
          &oh[base + (size_t)qrow * Esz + d * 16 + frow]);
    }
}

// ---------------------------------------------------------------------------
extern "C" void kernel_launch(void* const* d_in, const int* in_sizes, int n_in,
                              void* d_out, int out_size, void* d_ws, size_t ws_size,
                              hipStream_t stream)
{
  (void)in_sizes; (void)n_in; (void)out_size; (void)ws_size;

  const float* q  = (const float*)d_in[0];
  const float* k  = (const float*)d_in[1];
  const float* v  = (const float*)d_in[2];
  const float* Wq = (const float*)d_in[3];
  const float* bq = (const float*)d_in[4];
  const float* Wk = (const float*)d_in[5];
  const float* bk = (const float*)d_in[6];
  const float* Wv = (const float*)d_in[7];
  const float* bv = (const float*)d_in[8];
  const float* Wo = (const float*)d_in[9];
  const float* bo = (const float*)d_in[10];

  float* out  = (float*)d_out;
  float* attn = out + PLANE;  // output 1 follows output 0, flat

  unsigned short* qph = (unsigned short*)d_ws;
  unsigned short* kph = qph + PLANE;
  unsigned short* vpp = kph + PLANE;
  unsigned short* oh  = vpp + PLANE;

  dim3 bb(256);
  gemm_proj3<<<dim3(8, 64, 3), bb, 0, stream>>>(q, k, v, Wq, Wk, Wv,
                                                bq, bk, bv, qph, kph, vpp);

  dim3 ga(32, 64);
  attn_fused<<<ga, bb, 0, stream>>>(qph, kph, vpp, attn, oh);

  gemm_out<<<dim3(8, 64), bb, 0, stream>>>(oh, Wo, bo, out);
}